// Round 1
// baseline (249.234 us; speedup 1.0000x reference)
//
#include <hip/hip_runtime.h>

#define BB 128
#define SS 64
#define KK 10
#define DD 256
#define NN (BB*SS)        // 8192 rows
#define ROWS 32           // rows per block
#define NBLK (NN/ROWS)    // 256 blocks
#define NT 512            // threads per block (8 waves)

typedef __attribute__((ext_vector_type(8))) short short8;
typedef __attribute__((ext_vector_type(4))) float f32x4;

#define FRAG_ELEMS (48*8*64*8)   // 196608 bf16 values per weight matrix

__device__ __forceinline__ unsigned short f2bf(float f){
  union { float f; unsigned u; } v; v.f = f;
  unsigned r = (v.u + 0x7FFFu + ((v.u >> 16) & 1u)) >> 16;
  return (unsigned short)r;
}

// Pre-swizzle W_ih[:, :D] and W_hh into bf16 MFMA B-fragment order:
// frag value at (tn, tk, lane, j) = W[c = tn*16 + (lane&15)][d = tk*32 + (lane>>4)*8 + j]
// stored flat at ((tn*8+tk)*64 + lane)*8 + j.  FW1 first, FWhh second.
__global__ void prep_weights(const float* __restrict__ Wih,
                             const float* __restrict__ Whh,
                             unsigned short* __restrict__ fw){
  int id = blockIdx.x * 256 + threadIdx.x;     // 0 .. 2*FRAG_ELEMS-1
  int arr = (id >= FRAG_ELEMS);
  int r = arr ? (id - FRAG_ELEMS) : id;
  int j  = r & 7;
  int l  = (r >> 3) & 63;
  int tk = (r >> 9) & 7;
  int tn = r >> 12;                            // 0..47
  int c  = tn * 16 + (l & 15);                 // 0..767
  int d  = tk * 32 + ((l >> 4) << 3) + j;      // 0..255
  float v = arr ? Whh[c * 256 + d] : Wih[c * 512 + d];
  fw[id] = f2bf(v);
}

__global__ __launch_bounds__(NT, 2) void gru_main(
    const float* __restrict__ item, const float* __restrict__ user,
    const float* __restrict__ b_ih, const float* __restrict__ b_hh,
    const float* __restrict__ w_out, const float* __restrict__ b_out,
    const int* __restrict__ length, const unsigned short* __restrict__ ws,
    float* __restrict__ out)
{
  // x and h tiles stored in LDS already in A-fragment order:
  // elem (mt, tk, lane, j) at ((mt*8+tk)*64+lane)*8+j
  __shared__ unsigned short xfrag[2*8*64*8];   // 16 KB
  __shared__ unsigned short hfrag[2*8*64*8];   // 16 KB
  __shared__ float yp[8][2][4][4];             // [wave][mt][quad][reg], 1 KB

  const int tid  = threadIdx.x;
  const int lane = tid & 63;
  const int w    = tid >> 6;        // wave 0..7
  const int col  = lane & 15;       // column within 16-tile / C-layout col
  const int q    = lane >> 4;       // quad
  const int nb   = blockIdx.x * ROWS;
  const int b    = nb / SS;         // 32 | 64 -> one user per block

  const short8* fw1 = (const short8*)ws;
  const short8* fwh = fw1 + (FRAG_ELEMS/8);

  // per-group constants (each wave owns groups g = 2w, 2w+1; d = g*16+col)
  float br_[2], bz_[2], bin_[2], bhn_[2], wo_[2];
  #pragma unroll
  for (int gi = 0; gi < 2; ++gi){
    int d = (w*2 + gi)*16 + col;
    br_[gi]  = b_ih[d]       + b_hh[d];
    bz_[gi]  = b_ih[256 + d] + b_hh[256 + d];
    bin_[gi] = b_ih[512 + d];
    bhn_[gi] = b_hh[512 + d];
    wo_[gi]  = w_out[d];
  }

  // h0 = user_embs[b, clip(length[b]-1,0)]; identical for all 32 rows of this block
  int idx = length[b] - 1; if (idx < 0) idx = 0;
  float h[2][2][4];
  #pragma unroll
  for (int gi = 0; gi < 2; ++gi){
    float u0 = user[((size_t)b*SS + idx)*DD + (w*2 + gi)*16 + col];
    #pragma unroll
    for (int mt = 0; mt < 2; ++mt)
      #pragma unroll
      for (int reg = 0; reg < 4; ++reg)
        h[mt][gi][reg] = u0;
  }

  // write h0 into hfrag (A-fragment layout), owner-thread scatter
  #pragma unroll
  for (int mt = 0; mt < 2; ++mt)
    #pragma unroll
    for (int gi = 0; gi < 2; ++gi){
      int d   = (w*2 + gi)*16 + col;
      int tkk = d >> 5;
      int slb = ((d >> 3) & 3) * 16;
      #pragma unroll
      for (int reg = 0; reg < 4; ++reg){
        int m = q*4 + reg;
        hfrag[((mt*8 + tkk)*64 + slb + m)*8 + (d & 7)] = f2bf(h[mt][gi][reg]);
      }
    }

  // cooperative x-tile load: thread covers row = tid>>4, 16 d's at d0 = (tid&15)*16
  const int xrow = tid >> 4;
  const int xd0  = (tid & 15) * 16;
  {
    const float4* p = (const float4*)(item + ((size_t)(nb + xrow)*KK + 0)*DD + xd0);
    float4 xv0 = p[0], xv1 = p[1], xv2 = p[2], xv3 = p[3];
    unsigned short tmp[16];
    tmp[0]=f2bf(xv0.x); tmp[1]=f2bf(xv0.y); tmp[2]=f2bf(xv0.z); tmp[3]=f2bf(xv0.w);
    tmp[4]=f2bf(xv1.x); tmp[5]=f2bf(xv1.y); tmp[6]=f2bf(xv1.z); tmp[7]=f2bf(xv1.w);
    tmp[8]=f2bf(xv2.x); tmp[9]=f2bf(xv2.y); tmp[10]=f2bf(xv2.z); tmp[11]=f2bf(xv2.w);
    tmp[12]=f2bf(xv3.x); tmp[13]=f2bf(xv3.y); tmp[14]=f2bf(xv3.z); tmp[15]=f2bf(xv3.w);
    int m = xrow & 15, mt = xrow >> 4, o0 = (tid & 15)*2;
    #pragma unroll
    for (int oo = 0; oo < 2; ++oo){
      int o = o0 + oo, tkk = o >> 2, sl = (o & 3)*16 + m;
      *(short8*)&xfrag[((mt*8 + tkk)*64 + sl)*8] = *(short8*)&tmp[oo*8];
    }
  }
  __syncthreads();

  const float bout = b_out[0];

  for (int k = 0; k < KK; ++k){
    // accumulators: [mt][gi][kind]  kind: 0=r 1=z 2=i_n 3=h_n
    f32x4 acc[2][2][4];
    #pragma unroll
    for (int mt = 0; mt < 2; ++mt)
      #pragma unroll
      for (int gi = 0; gi < 2; ++gi)
        #pragma unroll
        for (int kd = 0; kd < 4; ++kd){
          f32x4 z4 = {0.f, 0.f, 0.f, 0.f};
          acc[mt][gi][kd] = z4;
        }

    #pragma unroll 2
    for (int tk = 0; tk < 8; ++tk){
      short8 ax[2], ah[2];
      #pragma unroll
      for (int mt = 0; mt < 2; ++mt){
        ax[mt] = *(const short8*)&xfrag[((mt*8 + tk)*64 + lane)*8];
        ah[mt] = *(const short8*)&hfrag[((mt*8 + tk)*64 + lane)*8];
      }
      #pragma unroll
      for (int gi = 0; gi < 2; ++gi){
        int g = w*2 + gi;
        short8 w1r = fw1[((g     )*8 + tk)*64 + lane];
        short8 w1z = fw1[((16 + g)*8 + tk)*64 + lane];
        short8 w1n = fw1[((32 + g)*8 + tk)*64 + lane];
        short8 whr = fwh[((g     )*8 + tk)*64 + lane];
        short8 whz = fwh[((16 + g)*8 + tk)*64 + lane];
        short8 whn = fwh[((32 + g)*8 + tk)*64 + lane];
        #pragma unroll
        for (int mt = 0; mt < 2; ++mt){
          acc[mt][gi][0] = __builtin_amdgcn_mfma_f32_16x16x32_bf16(ax[mt], w1r, acc[mt][gi][0], 0, 0, 0);
          acc[mt][gi][0] = __builtin_amdgcn_mfma_f32_16x16x32_bf16(ah[mt], whr, acc[mt][gi][0], 0, 0, 0);
          acc[mt][gi][1] = __builtin_amdgcn_mfma_f32_16x16x32_bf16(ax[mt], w1z, acc[mt][gi][1], 0, 0, 0);
          acc[mt][gi][1] = __builtin_amdgcn_mfma_f32_16x16x32_bf16(ah[mt], whz, acc[mt][gi][1], 0, 0, 0);
          acc[mt][gi][2] = __builtin_amdgcn_mfma_f32_16x16x32_bf16(ax[mt], w1n, acc[mt][gi][2], 0, 0, 0);
          acc[mt][gi][3] = __builtin_amdgcn_mfma_f32_16x16x32_bf16(ah[mt], whn, acc[mt][gi][3], 0, 0, 0);
        }
      }
    }

    // prefetch next x tile into registers (HBM latency hidden behind gates)
    float4 xn0, xn1, xn2, xn3;
    if (k < KK-1){
      const float4* p = (const float4*)(item + ((size_t)(nb + xrow)*KK + (k+1))*DD + xd0);
      xn0 = p[0]; xn1 = p[1]; xn2 = p[2]; xn3 = p[3];
    }

    // gates — entirely in-register (r,z,i_n,h_n for same (row,d) share lane+reg)
    float ypl[2][4];
    #pragma unroll
    for (int mt = 0; mt < 2; ++mt)
      #pragma unroll
      for (int reg = 0; reg < 4; ++reg) ypl[mt][reg] = 0.f;

    #pragma unroll
    for (int mt = 0; mt < 2; ++mt)
      #pragma unroll
      for (int gi = 0; gi < 2; ++gi)
        #pragma unroll
        for (int reg = 0; reg < 4; ++reg){
          float rp = acc[mt][gi][0][reg] + br_[gi];
          float zp = acc[mt][gi][1][reg] + bz_[gi];
          float r  = 1.f / (1.f + __expf(-rp));
          float z  = 1.f / (1.f + __expf(-zp));
          float np = acc[mt][gi][2][reg] + bin_[gi] + r*(acc[mt][gi][3][reg] + bhn_[gi]);
          np = fminf(fmaxf(np, -30.f), 30.f);
          float e  = __expf(2.f*np);
          float n  = (e - 1.f) / (e + 1.f);     // tanh
          float hv = (1.f - z)*n + z*h[mt][gi][reg];
          h[mt][gi][reg] = hv;
          ypl[mt][reg] += hv * wo_[gi];
        }

    // y partial: reduce across the 16 cols (lanes sharing q)
    #pragma unroll
    for (int mt = 0; mt < 2; ++mt)
      #pragma unroll
      for (int reg = 0; reg < 4; ++reg){
        float p = ypl[mt][reg];
        p += __shfl_xor(p, 1);
        p += __shfl_xor(p, 2);
        p += __shfl_xor(p, 4);
        p += __shfl_xor(p, 8);
        if (col == 0) yp[w][mt][q][reg] = p;
      }

    __syncthreads();   // B1: all GEMM reads + yp writes complete

    // write h' (bf16) into hfrag for next step
    #pragma unroll
    for (int mt = 0; mt < 2; ++mt)
      #pragma unroll
      for (int gi = 0; gi < 2; ++gi){
        int d   = (w*2 + gi)*16 + col;
        int tkk = d >> 5;
        int slb = ((d >> 3) & 3) * 16;
        #pragma unroll
        for (int reg = 0; reg < 4; ++reg){
          int m = q*4 + reg;
          hfrag[((mt*8 + tkk)*64 + slb + m)*8 + (d & 7)] = f2bf(h[mt][gi][reg]);
        }
      }

    // write next x tile
    if (k < KK-1){
      unsigned short tmp[16];
      tmp[0]=f2bf(xn0.x); tmp[1]=f2bf(xn0.y); tmp[2]=f2bf(xn0.z); tmp[3]=f2bf(xn0.w);
      tmp[4]=f2bf(xn1.x); tmp[5]=f2bf(xn1.y); tmp[6]=f2bf(xn1.z); tmp[7]=f2bf(xn1.w);
      tmp[8]=f2bf(xn2.x); tmp[9]=f2bf(xn2.y); tmp[10]=f2bf(xn2.z); tmp[11]=f2bf(xn2.w);
      tmp[12]=f2bf(xn3.x); tmp[13]=f2bf(xn3.y); tmp[14]=f2bf(xn3.z); tmp[15]=f2bf(xn3.w);
      int m = xrow & 15, mt = xrow >> 4, o0 = (tid & 15)*2;
      #pragma unroll
      for (int oo = 0; oo < 2; ++oo){
        int o = o0 + oo, tkk = o >> 2, sl = (o & 3)*16 + m;
        *(short8*)&xfrag[((mt*8 + tkk)*64 + sl)*8] = *(short8*)&tmp[oo*8];
      }
    }

    // finalize y for step k (reads yp written before B1; completes before B2)
    if (tid < 32){
      float s = bout;
      #pragma unroll
      for (int ww = 0; ww < 8; ++ww)
        s += yp[ww][tid >> 4][(tid >> 2) & 3][tid & 3];
      out[(size_t)(nb + tid)*KK + k] = s;
    }

    __syncthreads();   // B2: h/x frags visible before next GEMM
  }
}

extern "C" void kernel_launch(void* const* d_in, const int* in_sizes, int n_in,
                              void* d_out, int out_size, void* d_ws, size_t ws_size,
                              hipStream_t stream) {
  const float* item   = (const float*)d_in[0];
  const float* user   = (const float*)d_in[1];
  const float* W_ih   = (const float*)d_in[2];
  const float* W_hh   = (const float*)d_in[3];
  const float* b_ih   = (const float*)d_in[4];
  const float* b_hh   = (const float*)d_in[5];
  const float* w_out  = (const float*)d_in[6];
  const float* b_out  = (const float*)d_in[7];
  const int*   length = (const int*)d_in[8];
  unsigned short* ws  = (unsigned short*)d_ws;   // needs 768 KB
  float* out = (float*)d_out;

  hipLaunchKernelGGL(prep_weights, dim3((2*FRAG_ELEMS)/256), dim3(256), 0, stream,
                     W_ih, W_hh, ws);
  hipLaunchKernelGGL(gru_main, dim3(NBLK), dim3(NT), 0, stream,
                     item, user, b_ih, b_hh, w_out, b_out, length, ws, out);
}

// Round 3
// 230.145 us; speedup vs baseline: 1.0829x; 1.0829x over previous
//
#include <hip/hip_runtime.h>

#define BB 128
#define SS 64
#define KK 10
#define DD 256
#define NN (BB*SS)        // 8192 rows
#define ROWS 32           // rows per block
#define NBLK (NN/ROWS)    // 256 blocks = 1 per CU
#define NT 1024           // 16 waves per block -> 4 waves/SIMD

typedef __attribute__((ext_vector_type(8))) short short8;
typedef __attribute__((ext_vector_type(4))) float f32x4;

#define FRAG_ELEMS (48*8*64*8)   // 196608 bf16 values per weight matrix

__device__ __forceinline__ unsigned short f2bf(float f){
  union { float f; unsigned u; } v; v.f = f;
  unsigned r = (v.u + 0x7FFFu + ((v.u >> 16) & 1u)) >> 16;
  return (unsigned short)r;
}

// Pre-swizzle W_ih[:, :D] and W_hh into bf16 MFMA B-fragment order:
// frag value at (tn, tk, lane, j) = W[c = tn*16 + (lane&15)][d = tk*32 + (lane>>4)*8 + j]
// stored flat at ((tn*8+tk)*64 + lane)*8 + j.  FW1 first, FWhh second.
__global__ void prep_weights(const float* __restrict__ Wih,
                             const float* __restrict__ Whh,
                             unsigned short* __restrict__ fw){
  int id = blockIdx.x * 256 + threadIdx.x;     // 0 .. 2*FRAG_ELEMS-1
  int arr = (id >= FRAG_ELEMS);
  int r = arr ? (id - FRAG_ELEMS) : id;
  int j  = r & 7;
  int l  = (r >> 3) & 63;
  int tk = (r >> 9) & 7;
  int tn = r >> 12;                            // 0..47
  int c  = tn * 16 + (l & 15);                 // 0..767
  int d  = tk * 32 + ((l >> 4) << 3) + j;      // 0..255
  float v = arr ? Whh[c * 256 + d] : Wih[c * 512 + d];
  fw[id] = f2bf(v);
}

__global__ __launch_bounds__(NT, 4) void gru_main(
    const float* __restrict__ item, const float* __restrict__ user,
    const float* __restrict__ b_ih, const float* __restrict__ b_hh,
    const float* __restrict__ w_out, const float* __restrict__ b_out,
    const int* __restrict__ length, const unsigned short* __restrict__ ws,
    float* __restrict__ out)
{
  // A-fragment layout: elem (mt, tk, lane, j) at ((mt*8+tk)*64+lane)*8+j
  // double-buffered so one barrier/step suffices
  __shared__ unsigned short xfrag[2][2*8*64*8];   // 32 KB
  __shared__ unsigned short hfrag[2][2*8*64*8];   // 32 KB
  __shared__ float yp[3][16][2][4][4];            // 6 KB, triple-buffered

  const int tid  = threadIdx.x;
  const int lane = tid & 63;
  const int w    = tid >> 6;        // wave 0..15 == column group g
  const int col  = lane & 15;       // C-layout col
  const int q    = lane >> 4;       // quad
  const int nb   = blockIdx.x * ROWS;
  const int b    = nb / SS;         // one user per block (32 | 64)

  const short8* fw1 = (const short8*)ws;
  const short8* fwh = fw1 + (FRAG_ELEMS/8);

  // per-column constants (this thread owns output channel d for 8 rows)
  const int d    = w*16 + col;
  const float br_  = b_ih[d]       + b_hh[d];
  const float bz_  = b_ih[256 + d] + b_hh[256 + d];
  const float bin_ = b_ih[512 + d];
  const float bhn_ = b_hh[512 + d];
  const float wo_  = w_out[d];

  // h0 = user_embs[b, clip(length[b]-1,0)]; identical for all 32 rows
  int idx = length[b] - 1; if (idx < 0) idx = 0;
  const float u0 = user[((size_t)b*SS + idx)*DD + d];
  float h[2][4];
  #pragma unroll
  for (int mt = 0; mt < 2; ++mt)
    #pragma unroll
    for (int reg = 0; reg < 4; ++reg)
      h[mt][reg] = u0;

  // write h0 into hfrag[0] (A-fragment layout), owner-thread scatter
  const int tkk = d >> 5;
  const int slb = ((d >> 3) & 3) * 16;
  const int dj  = d & 7;
  {
    unsigned short hb = f2bf(u0);
    #pragma unroll
    for (int mt = 0; mt < 2; ++mt)
      #pragma unroll
      for (int reg = 0; reg < 4; ++reg)
        hfrag[0][((mt*8 + tkk)*64 + slb + q*4 + reg)*8 + dj] = hb;
  }

  // cooperative x-tile load: thread covers row = tid>>5, 8 d's at (tid&31)*8
  const int xrow = tid >> 5;        // 0..31
  const int xo   = tid & 31;        // which 8-wide d chunk
  const int xmt  = xrow >> 4;
  const int xtk  = xo >> 2;
  const int xsl  = (xo & 3)*16 + (xrow & 15);
  {
    const float4* p = (const float4*)(item + ((size_t)(nb + xrow)*KK + 0)*DD + xo*8);
    float4 a0 = p[0], a1 = p[1];
    unsigned short t[8];
    t[0]=f2bf(a0.x); t[1]=f2bf(a0.y); t[2]=f2bf(a0.z); t[3]=f2bf(a0.w);
    t[4]=f2bf(a1.x); t[5]=f2bf(a1.y); t[6]=f2bf(a1.z); t[7]=f2bf(a1.w);
    *(short8*)&xfrag[0][((xmt*8 + xtk)*64 + xsl)*8] = *(short8*)t;
  }
  __syncthreads();

  const float bout = b_out[0];

  for (int k = 0; k < KK; ++k){
    const int cb  = k & 1;
    const int nbf = cb ^ 1;

    // accumulators: [mt][kind]  kind: 0=r 1=z 2=i_n 3=h_n
    f32x4 acc[2][4];
    #pragma unroll
    for (int mt = 0; mt < 2; ++mt)
      #pragma unroll
      for (int kd = 0; kd < 4; ++kd){
        f32x4 z4 = {0.f, 0.f, 0.f, 0.f};
        acc[mt][kd] = z4;
      }

    #pragma unroll 2
    for (int tk = 0; tk < 8; ++tk){
      short8 ax0 = *(const short8*)&xfrag[cb][((0*8 + tk)*64 + lane)*8];
      short8 ax1 = *(const short8*)&xfrag[cb][((1*8 + tk)*64 + lane)*8];
      short8 ah0 = *(const short8*)&hfrag[cb][((0*8 + tk)*64 + lane)*8];
      short8 ah1 = *(const short8*)&hfrag[cb][((1*8 + tk)*64 + lane)*8];
      short8 w1r = fw1[((w     )*8 + tk)*64 + lane];
      short8 w1z = fw1[((16 + w)*8 + tk)*64 + lane];
      short8 w1n = fw1[((32 + w)*8 + tk)*64 + lane];
      short8 whr = fwh[((w     )*8 + tk)*64 + lane];
      short8 whz = fwh[((16 + w)*8 + tk)*64 + lane];
      short8 whn = fwh[((32 + w)*8 + tk)*64 + lane];
      acc[0][0] = __builtin_amdgcn_mfma_f32_16x16x32_bf16(ax0, w1r, acc[0][0], 0, 0, 0);
      acc[0][0] = __builtin_amdgcn_mfma_f32_16x16x32_bf16(ah0, whr, acc[0][0], 0, 0, 0);
      acc[0][1] = __builtin_amdgcn_mfma_f32_16x16x32_bf16(ax0, w1z, acc[0][1], 0, 0, 0);
      acc[0][1] = __builtin_amdgcn_mfma_f32_16x16x32_bf16(ah0, whz, acc[0][1], 0, 0, 0);
      acc[0][2] = __builtin_amdgcn_mfma_f32_16x16x32_bf16(ax0, w1n, acc[0][2], 0, 0, 0);
      acc[0][3] = __builtin_amdgcn_mfma_f32_16x16x32_bf16(ah0, whn, acc[0][3], 0, 0, 0);
      acc[1][0] = __builtin_amdgcn_mfma_f32_16x16x32_bf16(ax1, w1r, acc[1][0], 0, 0, 0);
      acc[1][0] = __builtin_amdgcn_mfma_f32_16x16x32_bf16(ah1, whr, acc[1][0], 0, 0, 0);
      acc[1][1] = __builtin_amdgcn_mfma_f32_16x16x32_bf16(ax1, w1z, acc[1][1], 0, 0, 0);
      acc[1][1] = __builtin_amdgcn_mfma_f32_16x16x32_bf16(ah1, whz, acc[1][1], 0, 0, 0);
      acc[1][2] = __builtin_amdgcn_mfma_f32_16x16x32_bf16(ax1, w1n, acc[1][2], 0, 0, 0);
      acc[1][3] = __builtin_amdgcn_mfma_f32_16x16x32_bf16(ah1, whn, acc[1][3], 0, 0, 0);
    }

    // prefetch next x tile into registers (HBM latency hidden behind gates)
    float4 xn0, xn1;
    if (k < KK-1){
      const float4* p = (const float4*)(item + ((size_t)(nb + xrow)*KK + (k+1))*DD + xo*8);
      xn0 = p[0]; xn1 = p[1];
    }

    // gates — entirely in-register
    float ypl[2][4];
    #pragma unroll
    for (int mt = 0; mt < 2; ++mt)
      #pragma unroll
      for (int reg = 0; reg < 4; ++reg){
        float rp = acc[mt][0][reg] + br_;
        float zp = acc[mt][1][reg] + bz_;
        float r  = 1.f / (1.f + __expf(-rp));
        float z  = 1.f / (1.f + __expf(-zp));
        float np = acc[mt][2][reg] + bin_ + r*(acc[mt][3][reg] + bhn_);
        np = fminf(fmaxf(np, -30.f), 30.f);
        float e  = __expf(2.f*np);
        float n  = (e - 1.f) / (e + 1.f);     // tanh
        float hv = (1.f - z)*n + z*h[mt][reg];
        h[mt][reg] = hv;
        ypl[mt][reg] = hv * wo_;
      }

    // y partial: reduce across the 16 cols of this wave's group
    #pragma unroll
    for (int mt = 0; mt < 2; ++mt)
      #pragma unroll
      for (int reg = 0; reg < 4; ++reg){
        float p = ypl[mt][reg];
        p += __shfl_xor(p, 1);
        p += __shfl_xor(p, 2);
        p += __shfl_xor(p, 4);
        p += __shfl_xor(p, 8);
        if (col == 0) yp[k % 3][w][mt][q][reg] = p;
      }

    // write h' (bf16) into hfrag[nbf] for next step
    #pragma unroll
    for (int mt = 0; mt < 2; ++mt)
      #pragma unroll
      for (int reg = 0; reg < 4; ++reg)
        hfrag[nbf][((mt*8 + tkk)*64 + slb + q*4 + reg)*8 + dj] = f2bf(h[mt][reg]);

    // write next x tile into xfrag[nbf]
    if (k < KK-1){
      unsigned short t[8];
      t[0]=f2bf(xn0.x); t[1]=f2bf(xn0.y); t[2]=f2bf(xn0.z); t[3]=f2bf(xn0.w);
      t[4]=f2bf(xn1.x); t[5]=f2bf(xn1.y); t[6]=f2bf(xn1.z); t[7]=f2bf(xn1.w);
      *(short8*)&xfrag[nbf][((xmt*8 + xtk)*64 + xsl)*8] = *(short8*)t;
    }

    // finalize y for step k-1 (yp[(k-1)%3] stable since previous barrier;
    // concurrent writes go to yp[k%3] which is a different buffer)
    if (k > 0 && tid < 32){
      float s = bout;
      #pragma unroll
      for (int ww = 0; ww < 16; ++ww)
        s += yp[(k-1) % 3][ww][tid >> 4][(tid >> 2) & 3][tid & 3];
      out[(size_t)(nb + tid)*KK + (k-1)] = s;
    }

    __syncthreads();   // single barrier per step
  }

  // finalize y for the last step
  if (tid < 32){
    float s = bout;
    #pragma unroll
    for (int ww = 0; ww < 16; ++ww)
      s += yp[(KK-1) % 3][ww][tid >> 4][(tid >> 2) & 3][tid & 3];
    out[(size_t)(nb + tid)*KK + (KK-1)] = s;
  }
}

extern "C" void kernel_launch(void* const* d_in, const int* in_sizes, int n_in,
                              void* d_out, int out_size, void* d_ws, size_t ws_size,
                              hipStream_t stream) {
  const float* item   = (const float*)d_in[0];
  const float* user   = (const float*)d_in[1];
  const float* W_ih   = (const float*)d_in[2];
  const float* W_hh   = (const float*)d_in[3];
  const float* b_ih   = (const float*)d_in[4];
  const float* b_hh   = (const float*)d_in[5];
  const float* w_out  = (const float*)d_in[6];
  const float* b_out  = (const float*)d_in[7];
  const int*   length = (const int*)d_in[8];
  unsigned short* ws  = (unsigned short*)d_ws;   // needs 768 KB
  float* out = (float*)d_out;

  hipLaunchKernelGGL(prep_weights, dim3((2*FRAG_ELEMS)/256), dim3(256), 0, stream,
                     W_ih, W_hh, ws);
  hipLaunchKernelGGL(gru_main, dim3(NBLK), dim3(NT), 0, stream,
                     item, user, b_ih, b_hh, w_out, b_out, length, ws, out);
}